// Round 19
// baseline (214.027 us; speedup 1.0000x reference)
//
#include <hip/hip_runtime.h>
#include <stdint.h>

typedef int v4i __attribute__((ext_vector_type(4)));

#define EPS_F32 1.1920928955078125e-07f   // np.finfo(float32).eps = 2^-23

// ---------------------------------------------------------------------------
// rss kernel: rss[k] = 1/ss[k] (exact IEEE div, once).
// ---------------------------------------------------------------------------
__global__ __launch_bounds__(256) void rss_kernel(
    const float* __restrict__ ss, float* __restrict__ rss, int DIN)
{
    const int i = blockIdx.x * 256 + threadIdx.x;
    if (i < DIN) rss[i] = 1.0f / ss[i];
}

// ---------------------------------------------------------------------------
// Fused quant kernel (r16, at memory floor).
// ---------------------------------------------------------------------------
__global__ __launch_bounds__(256) void quant_kernel(
    const float* __restrict__ X, const float* __restrict__ W,
    const float* __restrict__ ss, const float* __restrict__ rss,
    int8_t* __restrict__ Xq, float* __restrict__ xs,
    int8_t* __restrict__ Wq, float* __restrict__ ws,
    int DIN, int M)
{
    const int bid = blockIdx.x;
    const int tid = threadIdx.x;
    const bool isX = bid < M;
    const float* row  = isX ? X + (size_t)bid * DIN
                            : W + (size_t)(bid - M) * DIN;
    const float* svec = isX ? rss : ss;

    float4 v[4];
    float amax = 0.f;
#pragma unroll
    for (int c = 0; c < 4; ++c) {
        const int k = c * 1024 + tid * 4;
        float4 xv = *(const float4*)(row + k);
        float4 sv = *(const float4*)(svec + k);
        float4 q;
        q.x = xv.x * sv.x; q.y = xv.y * sv.y;
        q.z = xv.z * sv.z; q.w = xv.w * sv.w;
        v[c] = q;
        amax = fmaxf(amax, fmaxf(fmaxf(fabsf(q.x), fabsf(q.y)),
                                 fmaxf(fabsf(q.z), fabsf(q.w))));
    }
    __shared__ float red[4];
    for (int off = 32; off; off >>= 1) amax = fmaxf(amax, __shfl_xor(amax, off));
    const int lane = tid & 63, w = tid >> 6;
    if (lane == 0) red[w] = amax;
    __syncthreads();
    amax = fmaxf(fmaxf(red[0], red[1]), fmaxf(red[2], red[3]));

    float scale, lo;
    if (isX) { scale = fmaxf(amax, 1e-5f) / 127.0f;      lo = -127.f; }
    else     { scale = fmaxf(amax / 127.5f, EPS_F32);    lo = -128.f; }
    if (tid == 0) { if (isX) xs[bid] = scale; else ws[bid - M] = scale; }
    const float rscale = 1.0f / scale;

    int* qout = isX ? (int*)(Xq + (size_t)bid * DIN)
                    : (int*)(Wq + (size_t)(bid - M) * DIN);
#pragma unroll
    for (int c = 0; c < 4; ++c) {
        float4 q = v[c];
        int b0 = (int)fminf(fmaxf(rintf(q.x * rscale), lo), 127.f);
        int b1 = (int)fminf(fmaxf(rintf(q.y * rscale), lo), 127.f);
        int b2 = (int)fminf(fmaxf(rintf(q.z * rscale), lo), 127.f);
        int b3 = (int)fminf(fmaxf(rintf(q.w * rscale), lo), 127.f);
        qout[c * 256 + tid] = (b0 & 255) | ((b1 & 255) << 8) |
                              ((b2 & 255) << 16) | ((b3 & 255) << 24);
    }
}

// ---------------------------------------------------------------------------
// Persistent 2-tile int8 NT GEMM, 256x256 tile, BKB=64, 4-slot LDS
// (4 x 32KB), stage-2-ahead / read-1-ahead, 8 waves (2x4), grid 256.
//
// ROUND 19: guaranteed read-use distance.  Flat t in [0,128) (2 segs x 64
// kt64).  Per iteration:
//   1. STAGE kt(t+2) -> slot (t+2)&3        [4 calls, 32KB]
//   2. vmcnt(4)  [retires stage(t+1); leaves stage(t+2) in flight]
//      (t=126: vmcnt(0) — counted wait would be a no-op race, r5 lesson)
//   3. s_barrier  [slot (t+1)&3 published block-wide]
//   4. read frags(t+1) [12 ds_read_b128] ; sched_barrier(0)
//   5. 32 INDEPENDENT MFMAs on frags(t) — zero dependency on step 4;
//      read drain (~1150cy) < MFMA window (~1300cy) -> no stall at t+1.
// WAR: stage(t+2) targets slot (t-2)&3, whose reads retired before the
// t-1 barrier (consumed by MFMA(t-2)).  Epilogue(seg0) fires at t==63
// after MFMA; its stores are over-waited by t=64's vmcnt(4) (safe
// direction, one-time).  Double frag sets via unroll-2 static names.
// Swizzle (64B rows, pair-based): LDS(row,c) holds global chunk
// q^=((row>>1)&7) over q=(row&1)*4+c — involution on both sides;
// per-16-lane read phase = 2-way bank aliasing (free, m136).
// ---------------------------------------------------------------------------
#define BM 256
#define BN 256
#define BKB 64

#define MFMA __builtin_amdgcn_mfma_i32_16x16x64_i8

__global__ __launch_bounds__(512, 2) void gemm_i8_kernel(
    const int8_t* __restrict__ Xq, const int8_t* __restrict__ Wq,
    const float* __restrict__ xs, const float* __restrict__ ws,
    const float* __restrict__ bias, float* __restrict__ Y,
    int M, int N, int K)
{
    __shared__ __align__(16) int8_t smem[131072];   // 4 slots x (A16K + B16K)

    const int tid  = threadIdx.x;
    const int lane = tid & 63;
    const int w    = tid >> 6;
    const int wrow = w >> 2, wcol = w & 3;   // wave tile 128 rows x 64 cols

    const int bid    = blockIdx.x;
    const int xcd    = bid & 7, idx = bid >> 3;
    const int bmBase = (xcd >> 1) * 8 + (idx >> 3);
    const int bn     = (xcd & 1) * 8 + (idx & 7);

    // staging source mapping (inverse pair-swizzle): thread covers LDS
    // linear byte rowStart*64 + tid*16 = (row=rowStart+(tid>>2), c=tid&3).
    const int qS  = (((tid >> 2) & 1) << 2) | (tid & 3);
    const int qpS = qS ^ ((tid >> 3) & 7);
    const int srcRowOff = ((tid >> 2) & ~1) + (qpS >> 2);
    const int srcKOff   = (qpS & 3) << 4;

    // fragment read per-lane byte offset (verified involution with above):
    // byte = base*64 + (lane&14)*64 + ((((lane&1)<<2)|(lane>>4)) ^ ((lane>>1)&7))*16
    const int laneOff = ((lane & 14) << 6)
        + (((((lane & 1) << 2) | (lane >> 4)) ^ ((lane >> 1) & 7)) << 4);

    auto STAGE = [&](const int8_t* gtile, int region, int rowStart) {
        const int8_t* src = gtile + (size_t)(rowStart + srcRowOff) * K + srcKOff;
        __builtin_amdgcn_global_load_lds(
            (const __attribute__((address_space(1))) void*)src,
            (__attribute__((address_space(3))) void*)(smem + region + rowStart * 64 + (w << 10)),
            16, 0, 0);
    };

    v4i acc[8][4] = {};
    v4i fa0[8], fb0[4], fa1[8], fb1[4];   // double frag sets, static names

    const int8_t* bT0 = Wq + (size_t)bn * BN * K;
    const int rowb = (lane >> 4) << 2;
    const int col  = lane & 15;

    auto aTile = [&](int t) {
        return Xq + (size_t)(bmBase + ((t >> 6) << 2)) * BM * K
                  + (size_t)(t & 63) * BKB;
    };
    auto bTile = [&](int t) { return bT0 + (size_t)(t & 63) * BKB; };

    auto EPI = [&](int bm) {
        float wsv[4], bv[4];
#pragma unroll
        for (int nj = 0; nj < 4; ++nj) {
            const int n = bn * BN + (wcol << 6) + (nj << 4) + col;
            wsv[nj] = ws[n];
            bv[nj]  = bias[n];
        }
#pragma unroll
        for (int mi = 0; mi < 8; ++mi) {
            const int mbase = bm * BM + (wrow << 7) + (mi << 4) + rowb;
#pragma unroll
            for (int r = 0; r < 4; ++r) {
                const int m = mbase + r;
                const float xsm = xs[m];
                float* yrow = Y + (size_t)m * N;
#pragma unroll
                for (int nj = 0; nj < 4; ++nj) {
                    const int n = bn * BN + (wcol << 6) + (nj << 4) + col;
                    yrow[n] = (float)acc[mi][nj][r] * xsm * wsv[nj] + bv[nj];
                }
            }
        }
    };

    // prologue: stage t=0 -> slot0, t=1 -> slot1; wait slot0; read frags(0)
    {
        const int8_t* a0 = aTile(0); const int8_t* b0 = bTile(0);
        STAGE(a0, 0, 0);      STAGE(a0, 0, 128);
        STAGE(b0, 16384, 0);  STAGE(b0, 16384, 128);
        const int8_t* a1 = aTile(1); const int8_t* b1 = bTile(1);
        STAGE(a1, 32768, 0);          STAGE(a1, 32768, 128);
        STAGE(b1, 32768 + 16384, 0);  STAGE(b1, 32768 + 16384, 128);
        asm volatile("s_waitcnt vmcnt(4)" ::: "memory");   // slot0 landed
        __builtin_amdgcn_s_barrier();
#pragma unroll
        for (int mi = 0; mi < 8; ++mi)
            fa0[mi] = *(const v4i*)(smem + (wrow << 13) + (mi << 10) + laneOff);
#pragma unroll
        for (int nj = 0; nj < 4; ++nj)
            fb0[nj] = *(const v4i*)(smem + 16384 + (wcol << 12) + (nj << 10) + laneOff);
    }

#define ITER(T, CA, CB, NA, NB)                                              \
    {                                                                        \
        const int t_ = (T);                                                  \
        if (t_ + 2 < 128) {                                                  \
            const int s2 = ((t_ + 2) & 3) << 15;                             \
            const int8_t* a2 = aTile(t_ + 2);                                \
            const int8_t* b2 = bTile(t_ + 2);                                \
            STAGE(a2, s2, 0);          STAGE(a2, s2, 128);                   \
            STAGE(b2, s2 + 16384, 0);  STAGE(b2, s2 + 16384, 128);           \
            asm volatile("s_waitcnt vmcnt(4)" ::: "memory");                 \
        } else if (t_ + 1 < 128) {                                           \
            asm volatile("s_waitcnt vmcnt(0)" ::: "memory");                 \
        }                                                                    \
        __builtin_amdgcn_s_barrier();                                        \
        if (t_ + 1 < 128) {                                                  \
            const int s1 = ((t_ + 1) & 3) << 15;                             \
            _Pragma("unroll")                                                \
            for (int mi = 0; mi < 8; ++mi)                                   \
                NA[mi] = *(const v4i*)(smem + s1 + (wrow << 13) + (mi << 10) + laneOff); \
            _Pragma("unroll")                                                \
            for (int nj = 0; nj < 4; ++nj)                                   \
                NB[nj] = *(const v4i*)(smem + s1 + 16384 + (wcol << 12) + (nj << 10) + laneOff); \
            __builtin_amdgcn_sched_barrier(0);                               \
        }                                                                    \
        __builtin_amdgcn_s_setprio(1);                                       \
        _Pragma("unroll")                                                    \
        for (int mi = 0; mi < 8; ++mi)                                       \
            _Pragma("unroll")                                                \
            for (int nj = 0; nj < 4; ++nj)                                   \
                acc[mi][nj] = MFMA(CA[mi], CB[nj], acc[mi][nj], 0, 0, 0);    \
        __builtin_amdgcn_s_setprio(0);                                       \
        if (t_ == 63) {                                                      \
            EPI(bmBase);                                                     \
            _Pragma("unroll")                                                \
            for (int mi = 0; mi < 8; ++mi)                                   \
                _Pragma("unroll")                                            \
                for (int nj = 0; nj < 4; ++nj)                               \
                    acc[mi][nj] = (v4i){0, 0, 0, 0};                         \
        }                                                                    \
    }

    for (int t = 0; t < 128; t += 2) {
        ITER(t,     fa0, fb0, fa1, fb1);
        ITER(t + 1, fa1, fb1, fa0, fb0);
    }
#undef ITER

    EPI(bmBase + 4);   // seg1 epilogue
}

// ---------------------------------------------------------------------------
extern "C" void kernel_launch(void* const* d_in, const int* in_sizes, int n_in,
                              void* d_out, int out_size, void* d_ws, size_t ws_size,
                              hipStream_t stream) {
    const float* X    = (const float*)d_in[0];
    const float* W    = (const float*)d_in[1];
    const float* bias = (const float*)d_in[2];
    const float* ss   = (const float*)d_in[3];

    const int DIN  = in_sizes[3];              // 4096
    const int DOUT = in_sizes[2];              // 4096
    const int M    = in_sizes[0] / DIN;        // 8192

    int8_t* Xq  = (int8_t*)d_ws;
    int8_t* Wq  = Xq + (size_t)M * DIN;
    float*  xs  = (float*)(Wq + (size_t)DOUT * DIN);
    float*  ws  = xs + M;
    float*  rss = ws + DOUT;
    float*  Y   = (float*)d_out;

    rss_kernel<<<(DIN + 255) / 256, 256, 0, stream>>>(ss, rss, DIN);
    quant_kernel<<<M + DOUT, 256, 0, stream>>>(X, W, ss, rss, Xq, xs, Wq, ws, DIN, M);
    gemm_i8_kernel<<<(M / BM) * (DOUT / BN) / 2, 512, 0, stream>>>(Xq, Wq, xs, ws, bias, Y, M, DOUT, DIN);
}

// Round 20
// 173.399 us; speedup vs baseline: 1.2343x; 1.2343x over previous
//
#include <hip/hip_runtime.h>
#include <stdint.h>

typedef int v4i __attribute__((ext_vector_type(4)));

#define EPS_F32 1.1920928955078125e-07f   // np.finfo(float32).eps = 2^-23

// ---------------------------------------------------------------------------
// rss kernel: rss[k] = 1/ss[k] (exact IEEE div, once) so the X-quant path
// becomes a pure multiply.  ss > 0 always (ratio of positive absmaxes).
// ---------------------------------------------------------------------------
__global__ __launch_bounds__(256) void rss_kernel(
    const float* __restrict__ ss, float* __restrict__ rss, int DIN)
{
    const int i = blockIdx.x * 256 + threadIdx.x;
    if (i < DIN) rss[i] = 1.0f / ss[i];
}

// ---------------------------------------------------------------------------
// Fused quant kernel: blocks [0,M) per-token X quant (multiply by rss),
// blocks [M,M+DOUT) per-out-channel W quant (multiply by ss).  Both paths
// are the same branchless q = v*s; one reciprocal per thread for the scale.
// At the ~38us memory floor (240 MB @ ~6.3 TB/s).
// ---------------------------------------------------------------------------
__global__ __launch_bounds__(256) void quant_kernel(
    const float* __restrict__ X, const float* __restrict__ W,
    const float* __restrict__ ss, const float* __restrict__ rss,
    int8_t* __restrict__ Xq, float* __restrict__ xs,
    int8_t* __restrict__ Wq, float* __restrict__ ws,
    int DIN, int M)
{
    const int bid = blockIdx.x;
    const int tid = threadIdx.x;
    const bool isX = bid < M;
    const float* row  = isX ? X + (size_t)bid * DIN
                            : W + (size_t)(bid - M) * DIN;
    const float* svec = isX ? rss : ss;

    float4 v[4];
    float amax = 0.f;
#pragma unroll
    for (int c = 0; c < 4; ++c) {
        const int k = c * 1024 + tid * 4;
        float4 xv = *(const float4*)(row + k);
        float4 sv = *(const float4*)(svec + k);
        float4 q;
        q.x = xv.x * sv.x; q.y = xv.y * sv.y;
        q.z = xv.z * sv.z; q.w = xv.w * sv.w;
        v[c] = q;
        amax = fmaxf(amax, fmaxf(fmaxf(fabsf(q.x), fabsf(q.y)),
                                 fmaxf(fabsf(q.z), fabsf(q.w))));
    }
    __shared__ float red[4];
    for (int off = 32; off; off >>= 1) amax = fmaxf(amax, __shfl_xor(amax, off));
    const int lane = tid & 63, w = tid >> 6;
    if (lane == 0) red[w] = amax;
    __syncthreads();
    amax = fmaxf(fmaxf(red[0], red[1]), fmaxf(red[2], red[3]));

    float scale, lo;
    if (isX) { scale = fmaxf(amax, 1e-5f) / 127.0f;      lo = -127.f; }
    else     { scale = fmaxf(amax / 127.5f, EPS_F32);    lo = -128.f; }
    if (tid == 0) { if (isX) xs[bid] = scale; else ws[bid - M] = scale; }
    const float rscale = 1.0f / scale;   // one exact div; then 16 muls

    int* qout = isX ? (int*)(Xq + (size_t)bid * DIN)
                    : (int*)(Wq + (size_t)(bid - M) * DIN);
#pragma unroll
    for (int c = 0; c < 4; ++c) {
        float4 q = v[c];
        int b0 = (int)fminf(fmaxf(rintf(q.x * rscale), lo), 127.f);
        int b1 = (int)fminf(fmaxf(rintf(q.y * rscale), lo), 127.f);
        int b2 = (int)fminf(fmaxf(rintf(q.z * rscale), lo), 127.f);
        int b3 = (int)fminf(fmaxf(rintf(q.w * rscale), lo), 127.f);
        qout[c * 256 + tid] = (b0 & 255) | ((b1 & 255) << 8) |
                              ((b2 & 255) << 16) | ((b3 & 255) << 24);
    }
}

// ---------------------------------------------------------------------------
// Persistent 2-tile int8 NT GEMM — round-10 structure (best measured,
// replay-validated).  256x256 tiles, BKB=128, 8 waves (2x4), 128 KiB dbuf
// LDS, mfma_i32_16x16x64_i8, grid 256 (1 block/CU), K-half sub-steps:
//   S0: 8 stages(next tile) + read fHI(cur) + MFMA(fLO)  -> vmcnt(0)+barrier
//   S1: read fLO(next buf)                  + MFMA(fHI)
// Session conclusion (r7-r19, 11 variants): LDS-read (~2300cy/kt) and MFMA
// (~2600cy/kt) do not overlap under any intra-block reordering/geometry at
// HIP source level — 133us is this structure's floor.  Exact-int8 GEMM is
// bit-exact vs the reference fp32 einsum (|acc| < 2^31).
// ---------------------------------------------------------------------------
#define BM 256
#define BN 256
#define BKB 128

#define MFMA __builtin_amdgcn_mfma_i32_16x16x64_i8

__global__ __launch_bounds__(512, 2) void gemm_i8_kernel(
    const int8_t* __restrict__ Xq, const int8_t* __restrict__ Wq,
    const float* __restrict__ xs, const float* __restrict__ ws,
    const float* __restrict__ bias, float* __restrict__ Y,
    int M, int N, int K)
{
    __shared__ __align__(16) int8_t smem[131072];

    const int tid  = threadIdx.x;
    const int lane = tid & 63;
    const int w    = tid >> 6;
    const int wrow = w >> 2, wcol = w & 3;

    const int bid    = blockIdx.x;
    const int xcd    = bid & 7, idx = bid >> 3;        // idx in [0,32)
    const int bmBase = (xcd >> 1) * 8 + (idx >> 3);    // seg0 bm; seg1 = +4
    const int bn     = (xcd & 1) * 8 + (idx & 7);

    const int srcSwz = ((lane & 7) ^ (lane >> 3)) << 4;  // staging source swizzle
    const int chnk0  = ((lane >> 4) ^ (lane & 7)) << 4;  // frag read, k-slice 0
    const int chnk1  = chnk0 ^ 64;                       // k-slice 1
    const int aRB = ((wrow << 6) + (lane & 15)) << 7;    // A frag row-byte base
    const int bRB = ((wcol << 5) + (lane & 15)) << 7;    // B frag row-byte base

    auto STAGE = [&](const int8_t* gtile, int region, int rowStart) {
        const int8_t* src = gtile +
            (size_t)(rowStart + (w << 3) + (lane >> 3)) * K + srcSwz;
        __builtin_amdgcn_global_load_lds(
            (const __attribute__((address_space(1))) void*)src,
            (__attribute__((address_space(3))) void*)(smem + region + ((rowStart + (w << 3)) << 7)),
            16, 0, 0);
    };

    v4i acc[8][4] = {};
    v4i fLA[8], fHA[8], fLB[4], fHB[4];   // K-half fragment sets (static names)

    const int KT = K / BKB;   // 32
    const int8_t* bT0 = Wq + (size_t)bn * BN * K;   // same B panel both segs
    const int rowb = (lane >> 4) << 2;
    const int col  = lane & 15;

    // prologue: stage tile (seg0,kt0) into buf0; read fLO from buf0
    {
        const int8_t* aT0 = Xq + (size_t)bmBase * BM * K;
        STAGE(aT0, 0,     0);   STAGE(aT0, 0,     64);
        STAGE(aT0, 0,     128); STAGE(aT0, 0,     192);
        STAGE(bT0, 32768, 0);   STAGE(bT0, 32768, 64);
        STAGE(bT0, 32768, 128); STAGE(bT0, 32768, 192);
        asm volatile("s_waitcnt vmcnt(0)" ::: "memory");
        __builtin_amdgcn_s_barrier();
#pragma unroll
        for (int i = 0; i < 4; ++i) {
            fLA[i]     = *(const v4i*)(smem + aRB + i * 2048 + chnk0);
            fLA[4 + i] = *(const v4i*)(smem + aRB + 16384 + i * 2048 + chnk0);
        }
#pragma unroll
        for (int j = 0; j < 2; ++j) {
            fLB[j]     = *(const v4i*)(smem + 32768 + bRB + j * 2048 + chnk0);
            fLB[2 + j] = *(const v4i*)(smem + 32768 + bRB + 16384 + j * 2048 + chnk0);
        }
    }

    for (int seg = 0; seg < 2; ++seg) {
        const int bm = bmBase + seg * 4;
        const int8_t* aT0 = Xq + (size_t)bm * BM * K;

        for (int kt = 0; kt < KT; ++kt) {
            const int Ab  = (kt & 1) * 65536;
            const int Bb  = Ab + 32768;
            const int nAb = ((kt & 1) ^ 1) * 65536;
            const int nBb = nAb + 32768;
            const bool more = (kt + 1 < KT);
            const bool pf   = more || (seg == 0);
            const int8_t* aTn = more ? aT0 + (size_t)(kt + 1) * BKB
                                     : Xq + (size_t)(bmBase + 4) * BM * K;
            const int8_t* bTn = more ? bT0 + (size_t)(kt + 1) * BKB : bT0;

            // ---- S0: 8 stages; read fHI(cur); MFMA on fLO (K 0..64)
            if (pf) { STAGE(aTn, nAb, 0);   STAGE(aTn, nAb, 64);
                      STAGE(aTn, nAb, 128); STAGE(aTn, nAb, 192);
                      STAGE(bTn, nBb, 0);   STAGE(bTn, nBb, 64);
                      STAGE(bTn, nBb, 128); STAGE(bTn, nBb, 192); }
#pragma unroll
            for (int i = 0; i < 4; ++i) {
                fHA[i]     = *(const v4i*)(smem + Ab + aRB + i * 2048 + chnk1);
                fHA[4 + i] = *(const v4i*)(smem + Ab + aRB + 16384 + i * 2048 + chnk1);
            }
#pragma unroll
            for (int j = 0; j < 2; ++j) {
                fHB[j]     = *(const v4i*)(smem + Bb + bRB + j * 2048 + chnk1);
                fHB[2 + j] = *(const v4i*)(smem + Bb + bRB + 16384 + j * 2048 + chnk1);
            }
            __builtin_amdgcn_s_setprio(1);
#pragma unroll
            for (int i = 0; i < 8; ++i)
#pragma unroll
                for (int j = 0; j < 4; ++j)
                    acc[i][j] = MFMA(fLA[i], fLB[j], acc[i][j], 0, 0, 0);
            __builtin_amdgcn_s_setprio(0);
            asm volatile("s_waitcnt vmcnt(0)" ::: "memory");  // all 8 stages landed
            __builtin_amdgcn_s_barrier();

            // ---- S1: read fLO(next buf); MFMA on fHI (K 64..128)
            if (pf) {
#pragma unroll
                for (int i = 0; i < 4; ++i) {
                    fLA[i]     = *(const v4i*)(smem + nAb + aRB + i * 2048 + chnk0);
                    fLA[4 + i] = *(const v4i*)(smem + nAb + aRB + 16384 + i * 2048 + chnk0);
                }
#pragma unroll
                for (int j = 0; j < 2; ++j) {
                    fLB[j]     = *(const v4i*)(smem + nBb + bRB + j * 2048 + chnk0);
                    fLB[2 + j] = *(const v4i*)(smem + nBb + bRB + 16384 + j * 2048 + chnk0);
                }
            }
            __builtin_amdgcn_s_setprio(1);
#pragma unroll
            for (int i = 0; i < 8; ++i)
#pragma unroll
                for (int j = 0; j < 4; ++j)
                    acc[i][j] = MFMA(fHA[i], fHB[j], acc[i][j], 0, 0, 0);
            __builtin_amdgcn_s_setprio(0);
        }

        // ----- epilogue: dequant + bias (layout col=lane&15, row=(lane>>4)*4+reg)
        {
            float wsv[4], bv[4];
#pragma unroll
            for (int j = 0; j < 4; ++j) {
                const int n = bn * BN + ((j >> 1) << 7) + (wcol << 5) + ((j & 1) << 4) + col;
                wsv[j] = ws[n];
                bv[j]  = bias[n];
            }
#pragma unroll
            for (int i = 0; i < 8; ++i) {
                const int mbase = bm * BM + ((i >> 2) << 7) + (wrow << 6) + ((i & 3) << 4) + rowb;
#pragma unroll
                for (int r = 0; r < 4; ++r) {
                    const int m = mbase + r;
                    const float xsm = xs[m];
                    float* yrow = Y + (size_t)m * N;
#pragma unroll
                    for (int j = 0; j < 4; ++j) {
                        const int n = bn * BN + ((j >> 1) << 7) + (wcol << 5) + ((j & 1) << 4) + col;
                        yrow[n] = (float)acc[i][j][r] * xsm * wsv[j] + bv[j];
                    }
                }
            }
        }

        if (seg == 0) {
#pragma unroll
            for (int i = 0; i < 8; ++i)
#pragma unroll
                for (int j = 0; j < 4; ++j)
                    acc[i][j] = (v4i){0, 0, 0, 0};
        }
    }
}

// ---------------------------------------------------------------------------
extern "C" void kernel_launch(void* const* d_in, const int* in_sizes, int n_in,
                              void* d_out, int out_size, void* d_ws, size_t ws_size,
                              hipStream_t stream) {
    const float* X    = (const float*)d_in[0];
    const float* W    = (const float*)d_in[1];
    const float* bias = (const float*)d_in[2];
    const float* ss   = (const float*)d_in[3];

    const int DIN  = in_sizes[3];              // 4096
    const int DOUT = in_sizes[2];              // 4096
    const int M    = in_sizes[0] / DIN;        // 8192

    int8_t* Xq  = (int8_t*)d_ws;
    int8_t* Wq  = Xq + (size_t)M * DIN;
    float*  xs  = (float*)(Wq + (size_t)DOUT * DIN);
    float*  ws  = xs + M;
    float*  rss = ws + DOUT;
    float*  Y   = (float*)d_out;

    rss_kernel<<<(DIN + 255) / 256, 256, 0, stream>>>(ss, rss, DIN);
    quant_kernel<<<M + DOUT, 256, 0, stream>>>(X, W, ss, rss, Xq, xs, Wq, ws, DIN, M);
    gemm_i8_kernel<<<(M / BM) * (DOUT / BN) / 2, 512, 0, stream>>>(Xq, Wq, xs, ws, bias, Y, M, DOUT, DIN);
}